// Round 1
// baseline (147.034 us; speedup 1.0000x reference)
//
#include <hip/hip_runtime.h>

#define N_DIM 32
#define NPB 64               // fine bucket: nodes per bucket
#define NB_FINE_MAX 2048     // max fine buckets
#define NC_MAX 128           // max coarse buckets
#define CSH 10               // coarse bucket = 1024 nodes
#define CAPC 18432           // tmp slots per coarse bucket (mean 16384, +16 sigma)
#define CAPFINE 1280         // pairs slots per fine bucket (mean 1024, +8 sigma)
#define CEPB 4096            // edges per coarse-part block
#define FT 512               // fused kernel threads
#define GROWS 512            // gemm rows per block (FT threads, 1 row/thread)
#define CAPF 2048            // fpart chunk
#define MAXCH 10             // fpart y-grid
#define ACCW 36              // padded LDS accumulator row stride (floats)

__device__ __forceinline__ unsigned f2bf_rne(float f) {
    unsigned u = __float_as_uint(f);
    return (u + 0x7FFFu + ((u >> 16) & 1u)) >> 16;
}
__device__ __forceinline__ float bf2f(unsigned h) {
    return __uint_as_float(h << 16);
}

// ---- Fused pass: blocks [0,nblk_g) = GEMM (Y=X@W -> bf16 rows);
// ----             blocks [nblk_g,..) = coarse partition (no dependence). ----
__global__ __launch_bounds__(FT) void k_fused(const float* __restrict__ X,
                                              const float* __restrict__ W,
                                              unsigned* __restrict__ Y,
                                              const int* __restrict__ src,
                                              const int* __restrict__ dst,
                                              int* __restrict__ cursorC0,
                                              int* __restrict__ tmp,
                                              int n_nodes, int n_edges,
                                              int ncoarse, int nblk_g) {
    __shared__ float Wlds[N_DIM * N_DIM];
    __shared__ int h[NC_MAX];
    __shared__ int gb[NC_MAX];
    const int t = threadIdx.x;

    if (blockIdx.x < nblk_g) {
        // ---------------- GEMM half ----------------
        for (int i = t; i < N_DIM * N_DIM; i += FT) Wlds[i] = W[i];
        __syncthreads();
        const int r = blockIdx.x * GROWS + t;
        if (r >= n_nodes) return;

        float x[N_DIM];
        const float4* xr = (const float4*)(X + (size_t)r * N_DIM);
#pragma unroll
        for (int i = 0; i < N_DIM / 4; ++i) {
            float4 v = xr[i];
            x[4 * i + 0] = v.x; x[4 * i + 1] = v.y;
            x[4 * i + 2] = v.z; x[4 * i + 3] = v.w;
        }
        float acc[N_DIM];
#pragma unroll
        for (int c = 0; c < N_DIM; ++c) acc[c] = 0.0f;
#pragma unroll
        for (int k = 0; k < N_DIM; ++k) {
            const float xk = x[k];
#pragma unroll
            for (int c = 0; c < N_DIM; ++c)
                acc[c] = fmaf(xk, Wlds[k * N_DIM + c], acc[c]);
        }
        unsigned yp[16];
#pragma unroll
        for (int q = 0; q < 16; ++q)
            yp[q] = f2bf_rne(acc[2 * q]) | (f2bf_rne(acc[2 * q + 1]) << 16);
        uint4* yr = (uint4*)(Y + (size_t)r * 16);
#pragma unroll
        for (int i = 0; i < 4; ++i)
            yr[i] = make_uint4(yp[4 * i], yp[4 * i + 1],
                               yp[4 * i + 2], yp[4 * i + 3]);
    } else {
        // ---------------- coarse-partition half ----------------
        if (t < NC_MAX) h[t] = 0;
        __syncthreads();
        const int start = (blockIdx.x - nblk_g) * CEPB;

        int vw[CEPB / FT], cw[CEPB / FT], rw[CEPB / FT];
#pragma unroll
        for (int k = 0; k < CEPB / FT; ++k) {
            int e = start + t + k * FT;
            if (e < n_edges) {
                int d = dst[e];
                int c = d >> CSH;
                cw[k] = c;
                vw[k] = src[e] | ((d & 1023) << 17);
                rw[k] = atomicAdd(&h[c], 1);
            } else {
                cw[k] = -1;
            }
        }
        __syncthreads();
        if (t < ncoarse) {
            int c = h[t];
            gb[t] = c ? atomicAdd(&cursorC0[t], c) : 0;
        }
        __syncthreads();
#pragma unroll
        for (int k = 0; k < CEPB / FT; ++k)
            if (cw[k] >= 0) {
                int idx = gb[cw[k]] + rw[k];
                if (idx < CAPC) tmp[cw[k] * CAPC + idx] = vw[k];
            }
    }
}

// ---- Fine refine: 16 bins per coarse chunk, rank-reuse, direct global write ----
__global__ __launch_bounds__(256) void k_fpart(const int* __restrict__ tmp,
                                               const int* __restrict__ cursorC0,
                                               int* __restrict__ cursorF0,
                                               int* __restrict__ pairs,
                                               int ncoarse) {
    __shared__ int cnt[16], gpos[16];
    const int t = threadIdx.x;
    const int c = blockIdx.x;
    const int lenC = min(cursorC0[c], CAPC);

    for (int chunk = blockIdx.y; chunk * CAPF < lenC; chunk += gridDim.y) {
        const int start = chunk * CAPF;
        const int n = min(CAPF, lenC - start);
        if (t < 16) cnt[t] = 0;
        __syncthreads();
        int pv[CAPF / 256], rv[CAPF / 256];
#pragma unroll
        for (int k = 0; k < CAPF / 256; ++k) {
            int i = t + k * 256;
            if (i < n) {
                int p = tmp[c * CAPC + start + i];
                pv[k] = p;
                rv[k] = atomicAdd(&cnt[(p >> 23) & 15], 1);
            } else {
                pv[k] = -1;
            }
        }
        __syncthreads();
        if (t < 16) gpos[t] = cnt[t] ? atomicAdd(&cursorF0[16 * c + t], cnt[t]) : 0;
        __syncthreads();
#pragma unroll
        for (int k = 0; k < CAPF / 256; ++k) {
            if (pv[k] >= 0) {
                int p = pv[k];
                int f = (p >> 23) & 15;
                int idx = gpos[f] + rv[k];
                if (idx < CAPFINE)
                    pairs[(size_t)(16 * c + f) * CAPFINE + idx] = p & 0x7FFFFF;
            }
        }
        __syncthreads();
    }
}

// ---- Aggregate: counting-sort + balanced-chunk edge-parallel consume ----
__device__ __forceinline__ void addv(float* acc, uint4 v) {
    acc[0] += bf2f(v.x & 0xFFFFu); acc[1] += bf2f(v.x >> 16);
    acc[2] += bf2f(v.y & 0xFFFFu); acc[3] += bf2f(v.y >> 16);
    acc[4] += bf2f(v.z & 0xFFFFu); acc[5] += bf2f(v.z >> 16);
    acc[6] += bf2f(v.w & 0xFFFFu); acc[7] += bf2f(v.w >> 16);
}

__device__ __forceinline__ void flush8(float* __restrict__ accS, int node, int l,
                                       float* __restrict__ a) {
    float* ap = accS + node * ACCW + l * 8;
#pragma unroll
    for (int j = 0; j < 8; ++j) {
        atomicAdd(ap + j, a[j]);
        a[j] = 0.0f;
    }
}

__global__ __launch_bounds__(256) void k_agg(const uint4* __restrict__ Y4,
                                             const int* __restrict__ cursorF0,
                                             const int* __restrict__ pairs,
                                             float* __restrict__ out,
                                             int n_nodes) {
    __shared__ int sbin[CAPFINE];
    __shared__ int cnt[NPB];
    __shared__ int excl[NPB];
    __shared__ float accS[NPB * ACCW];

    const int t = threadIdx.x;
    const int b = blockIdx.x;
    const int len = min(cursorF0[b], CAPFINE);
    const size_t segbase = (size_t)b * CAPFINE;
    const int l = t & 3;           // quarter-row (16 B)

    if (t < NPB) cnt[t] = 0;
    for (int i = t; i < NPB * ACCW; i += 256) accS[i] = 0.0f;
    __syncthreads();

    int pv[CAPFINE / 256], rv[CAPFINE / 256];
#pragma unroll
    for (int k = 0; k < CAPFINE / 256; ++k) {
        int i = t + k * 256;
        if (i < len) {
            int p = pairs[segbase + i];
            pv[k] = p;
            rv[k] = atomicAdd(&cnt[p >> 17], 1);
        } else {
            pv[k] = -1;
        }
    }
    __syncthreads();
    // exclusive scan of 64 counts in wave 0
    if (t < 64) {
        int c0 = cnt[t];
        int c = c0;
#pragma unroll
        for (int off = 1; off < 64; off <<= 1) {
            int u = __shfl_up(c, off, 64);
            if (t >= off) c += u;
        }
        excl[t] = c - c0;
    }
    __syncthreads();
#pragma unroll
    for (int k = 0; k < CAPFINE / 256; ++k) {
        if (pv[k] >= 0) {
            int p = pv[k];
            sbin[excl[p >> 17] + rv[k]] = p;   // keep node bits for chunk consume
        }
    }
    __syncthreads();

    // balanced chunks: slot s (4 lanes) takes an equal slice of the sorted sbin;
    // register-accumulate, flush to LDS on node-boundary crossings.
    const int s = t >> 2;
    const int clen = (len + NPB - 1) >> 6;
    const int e0 = s * clen;
    const int e1 = min(e0 + clen, len);

    float a[8];
#pragma unroll
    for (int i = 0; i < 8; ++i) a[i] = 0.0f;
    int cur = -1;

    for (int e = e0; e < e1; e += 4) {
        const int m = e1 - e;
        int p0 = sbin[e];
        int p1 = sbin[e + ((m > 1) ? 1 : 0)];
        int p2 = sbin[e + ((m > 2) ? 2 : 0)];
        int p3 = sbin[e + ((m > 3) ? 3 : 0)];
        uint4 v0 = Y4[(size_t)(p0 & 0x1FFFF) * 4 + l];
        uint4 v1 = Y4[(size_t)(p1 & 0x1FFFF) * 4 + l];
        uint4 v2 = Y4[(size_t)(p2 & 0x1FFFF) * 4 + l];
        uint4 v3 = Y4[(size_t)(p3 & 0x1FFFF) * 4 + l];
        int n0 = p0 >> 17;
        if (n0 != cur) {
            if (cur >= 0) flush8(accS, cur, l, a);
            cur = n0;
        }
        addv(a, v0);
        if (m > 1) {
            int n1 = p1 >> 17;
            if (n1 != cur) { flush8(accS, cur, l, a); cur = n1; }
            addv(a, v1);
        }
        if (m > 2) {
            int n2 = p2 >> 17;
            if (n2 != cur) { flush8(accS, cur, l, a); cur = n2; }
            addv(a, v2);
        }
        if (m > 3) {
            int n3 = p3 >> 17;
            if (n3 != cur) { flush8(accS, cur, l, a); cur = n3; }
            addv(a, v3);
        }
    }
    if (cur >= 0) flush8(accS, cur, l, a);
    __syncthreads();

    // readout: float4 from padded LDS rows -> coalesced float4 stores
    const int base = b * NPB;
    for (int q = t; q < NPB * 8; q += 256) {
        const int node = q >> 3;
        const int k4 = q & 7;
        const int gnode = base + node;
        if (gnode < n_nodes) {
            float4 v = *(const float4*)&accS[node * ACCW + k4 * 4];
            ((float4*)out)[(size_t)gnode * 8 + k4] = v;
        }
    }
}

extern "C" void kernel_launch(void* const* d_in, const int* in_sizes, int n_in,
                              void* d_out, int out_size, void* d_ws, size_t ws_size,
                              hipStream_t stream) {
    const float* X   = (const float*)d_in[0];
    const float* W   = (const float*)d_in[1];
    const int*   src = (const int*)d_in[2];
    const int*   dst = (const int*)d_in[3];
    float* out = (float*)d_out;

    const int n_nodes = in_sizes[0] / N_DIM;
    const int n_edges = in_sizes[2];
    const int nb = (n_nodes + NPB - 1) / NPB;        // 1563 fine buckets
    const int ncoarse = (n_nodes + 1023) / 1024;     // 98 coarse buckets

    // workspace layout
    unsigned* Y   = (unsigned*)d_ws;                  // n_nodes*16 uints (6.4 MB)
    int* cursorC0 = (int*)(Y + (size_t)n_nodes * 16); // NC_MAX
    int* cursorF0 = cursorC0 + NC_MAX;                // NB_FINE_MAX
    int* tmp      = cursorF0 + NB_FINE_MAX;           // ncoarse * CAPC (7.2 MB)
    int* pairs    = tmp + (size_t)ncoarse * CAPC;     // nb * CAPFINE (8.0 MB)

    const int nblk_g = (n_nodes + GROWS - 1) / GROWS; // 196
    const int nblk_c = (n_edges + CEPB - 1) / CEPB;   // 391

    // zero both cursor arrays (8.7 KB)
    hipMemsetAsync(cursorC0, 0, (size_t)(NC_MAX + NB_FINE_MAX) * sizeof(int), stream);

    k_fused<<<nblk_g + nblk_c, FT, 0, stream>>>(X, W, Y, src, dst, cursorC0, tmp,
                                                n_nodes, n_edges, ncoarse, nblk_g);
    k_fpart<<<dim3(ncoarse, MAXCH), 256, 0, stream>>>(tmp, cursorC0, cursorF0,
                                                      pairs, ncoarse);
    k_agg<<<nb, 256, 0, stream>>>((const uint4*)Y, cursorF0, pairs, out, n_nodes);
}

// Round 2
// 134.975 us; speedup vs baseline: 1.0893x; 1.0893x over previous
//
#include <hip/hip_runtime.h>

#define N_DIM 32
#define NPB 64               // fine bucket: nodes per bucket
#define NC_MAX 128           // max coarse buckets
#define CSH 10               // coarse bucket = 1024 nodes
#define CAPC 18432           // tmp slots per coarse bucket (mean 16384, +16 sigma)
#define CAPFINE 1280         // fine-bin queue slots (mean 1024, +8 sigma)
#define CEPB 4096            // edges per coarse-part block
#define FT 512               // fused kernel threads
#define GROWS 512            // gemm rows per block (FT threads, 1 row/thread)

__device__ __forceinline__ unsigned f2bf_rne(float f) {
    unsigned u = __float_as_uint(f);
    return (u + 0x7FFFu + ((u >> 16) & 1u)) >> 16;
}
__device__ __forceinline__ float bf2f(unsigned h) {
    return __uint_as_float(h << 16);
}

// ---- Fused pass: blocks [0,nblk_g) = GEMM (Y=X@W -> bf16 rows);
// ----             blocks [nblk_g,..) = coarse partition (no dependence). ----
__global__ __launch_bounds__(FT) void k_fused(const float* __restrict__ X,
                                              const float* __restrict__ W,
                                              unsigned* __restrict__ Y,
                                              const int* __restrict__ src,
                                              const int* __restrict__ dst,
                                              int* __restrict__ cursorC0,
                                              int* __restrict__ tmp,
                                              int n_nodes, int n_edges,
                                              int ncoarse, int nblk_g) {
    __shared__ float Wlds[N_DIM * N_DIM];
    __shared__ int h[NC_MAX];
    __shared__ int gb[NC_MAX];
    const int t = threadIdx.x;

    if (blockIdx.x < nblk_g) {
        // ---------------- GEMM half ----------------
        for (int i = t; i < N_DIM * N_DIM; i += FT) Wlds[i] = W[i];
        __syncthreads();
        const int r = blockIdx.x * GROWS + t;
        if (r >= n_nodes) return;

        float x[N_DIM];
        const float4* xr = (const float4*)(X + (size_t)r * N_DIM);
#pragma unroll
        for (int i = 0; i < N_DIM / 4; ++i) {
            float4 v = xr[i];
            x[4 * i + 0] = v.x; x[4 * i + 1] = v.y;
            x[4 * i + 2] = v.z; x[4 * i + 3] = v.w;
        }
        float acc[N_DIM];
#pragma unroll
        for (int c = 0; c < N_DIM; ++c) acc[c] = 0.0f;
#pragma unroll
        for (int k = 0; k < N_DIM; ++k) {
            const float xk = x[k];
#pragma unroll
            for (int c = 0; c < N_DIM; ++c)
                acc[c] = fmaf(xk, Wlds[k * N_DIM + c], acc[c]);
        }
        unsigned yp[16];
#pragma unroll
        for (int q = 0; q < 16; ++q)
            yp[q] = f2bf_rne(acc[2 * q]) | (f2bf_rne(acc[2 * q + 1]) << 16);
        uint4* yr = (uint4*)(Y + (size_t)r * 16);
#pragma unroll
        for (int i = 0; i < 4; ++i)
            yr[i] = make_uint4(yp[4 * i], yp[4 * i + 1],
                               yp[4 * i + 2], yp[4 * i + 3]);
    } else {
        // ---------------- coarse-partition half ----------------
        if (t < NC_MAX) h[t] = 0;
        __syncthreads();
        const int start = (blockIdx.x - nblk_g) * CEPB;

        int vw[CEPB / FT], cw[CEPB / FT], rw[CEPB / FT];
#pragma unroll
        for (int k = 0; k < CEPB / FT; ++k) {
            int e = start + t + k * FT;
            if (e < n_edges) {
                int d = dst[e];
                int c = d >> CSH;
                cw[k] = c;
                vw[k] = src[e] | ((d & 1023) << 17);
                rw[k] = atomicAdd(&h[c], 1);
            } else {
                cw[k] = -1;
            }
        }
        __syncthreads();
        if (t < ncoarse) {
            int c = h[t];
            gb[t] = c ? atomicAdd(&cursorC0[t], c) : 0;
        }
        __syncthreads();
#pragma unroll
        for (int k = 0; k < CEPB / FT; ++k)
            if (cw[k] >= 0) {
                int idx = gb[cw[k]] + rw[k];
                if (idx < CAPC) tmp[cw[k] * CAPC + idx] = vw[k];
            }
    }
}

// ---- Aggregate (fused fine-partition): block b = coarse c = b>>4, fine f = b&15.
// ---- Scan the L2/L3-resident coarse segment, filter fine bin into an LDS queue,
// ---- counting-sort by local node, node-parallel register gather-accumulate. ----
__device__ __forceinline__ void addv(float* acc, uint4 v) {
    acc[0] += bf2f(v.x & 0xFFFFu); acc[1] += bf2f(v.x >> 16);
    acc[2] += bf2f(v.y & 0xFFFFu); acc[3] += bf2f(v.y >> 16);
    acc[4] += bf2f(v.z & 0xFFFFu); acc[5] += bf2f(v.z >> 16);
    acc[6] += bf2f(v.w & 0xFFFFu); acc[7] += bf2f(v.w >> 16);
}

__global__ __launch_bounds__(256) void k_agg(const uint4* __restrict__ Y4,
                                             const int* __restrict__ cursorC0,
                                             const int* __restrict__ tmp,
                                             float* __restrict__ out,
                                             int n_nodes) {
    __shared__ int qbuf[CAPFINE];
    __shared__ int sbin[CAPFINE];
    __shared__ int cnt[NPB];
    __shared__ int cst[NPB];
    __shared__ int excl[NPB];
    __shared__ int qcnt;

    const int t = threadIdx.x;
    const int b = blockIdx.x;
    const int c = b >> 4;
    const int f = b & 15;
    const int lane = t & 63;
    const int lenC = min(cursorC0[c], CAPC);

    if (t < NPB) cnt[t] = 0;
    if (t == 0) qcnt = 0;
    __syncthreads();

    // scan coarse segment (int4), wave-aggregated push of fine-bin matches
    const int4* seg = (const int4*)(tmp + (size_t)c * CAPC);
    const int nIt = (lenC + 1023) >> 10;    // 256 threads * 4 elems
    for (int k = 0; k < nIt; ++k) {
        const int i4 = t + (k << 8);
        const int i0 = i4 << 2;
        int4 v = make_int4(0, 0, 0, 0);
        if (i0 < lenC) v = seg[i4];
        int ps[4] = {v.x, v.y, v.z, v.w};
#pragma unroll
        for (int j = 0; j < 4; ++j) {
            const int p = ps[j];
            const bool m = (i0 + j < lenC) && (((p >> 23) & 15) == f);
            unsigned long long msk = __ballot(m);
            if (m) {
                int pos = __popcll(msk & ((1ull << lane) - 1ull));
                int leader = __ffsll((unsigned long long)msk) - 1;
                int base;
                if (lane == leader) base = atomicAdd(&qcnt, __popcll(msk));
                base = __shfl(base, leader, 64);
                int idx = base + pos;
                if (idx < CAPFINE) qbuf[idx] = p;
            }
        }
    }
    __syncthreads();
    const int len = min(qcnt, CAPFINE);

    // counting sort by local node (6 bits), rank-reuse
    int pv[CAPFINE / 256], rv[CAPFINE / 256];
#pragma unroll
    for (int k = 0; k < CAPFINE / 256; ++k) {
        int i = t + k * 256;
        if (i < len) {
            int p = qbuf[i];
            pv[k] = p;
            rv[k] = atomicAdd(&cnt[(p >> 17) & 63], 1);
        } else {
            pv[k] = -1;
        }
    }
    __syncthreads();
    // inclusive scan of 64 counts in wave 0
    if (t < 64) {
        int c0 = cnt[t];
        int cc = c0;
#pragma unroll
        for (int off = 1; off < 64; off <<= 1) {
            int u = __shfl_up(cc, off, 64);
            if (t >= off) cc += u;
        }
        cst[t] = cc;
        excl[t] = cc - c0;
    }
    __syncthreads();
#pragma unroll
    for (int k = 0; k < CAPFINE / 256; ++k) {
        if (pv[k] >= 0) {
            int p = pv[k];
            sbin[excl[(p >> 17) & 63] + rv[k]] = p & 0x1FFFF;
        }
    }
    __syncthreads();

    // node-parallel gather: 4-lane group per node, 4 gathers in flight
    const int g = t >> 2;          // local node 0..63
    const int l = t & 3;           // quarter-row (16 B)
    float acc[8];
#pragma unroll
    for (int i = 0; i < 8; ++i) acc[i] = 0.0f;

    const int s1 = cst[g];
    const int s0 = s1 - cnt[g];
    for (int e = s0; e < s1; e += 4) {
        const int m = s1 - e;
        int i0 = sbin[e];
        int i1 = sbin[e + ((m > 1) ? 1 : 0)];
        int i2 = sbin[e + ((m > 2) ? 2 : 0)];
        int i3 = sbin[e + ((m > 3) ? 3 : 0)];
        uint4 v0 = Y4[(size_t)i0 * 4 + l];
        uint4 v1 = Y4[(size_t)i1 * 4 + l];
        uint4 v2 = Y4[(size_t)i2 * 4 + l];
        uint4 v3 = Y4[(size_t)i3 * 4 + l];
        addv(acc, v0);
        if (m > 1) addv(acc, v1);
        if (m > 2) addv(acc, v2);
        if (m > 3) addv(acc, v3);
    }

    const int node = b * NPB + g;
    if (node < n_nodes) {
        ((float4*)out)[(size_t)node * 8 + 2 * l] =
            make_float4(acc[0], acc[1], acc[2], acc[3]);
        ((float4*)out)[(size_t)node * 8 + 2 * l + 1] =
            make_float4(acc[4], acc[5], acc[6], acc[7]);
    }
}

extern "C" void kernel_launch(void* const* d_in, const int* in_sizes, int n_in,
                              void* d_out, int out_size, void* d_ws, size_t ws_size,
                              hipStream_t stream) {
    const float* X   = (const float*)d_in[0];
    const float* W   = (const float*)d_in[1];
    const int*   src = (const int*)d_in[2];
    const int*   dst = (const int*)d_in[3];
    float* out = (float*)d_out;

    const int n_nodes = in_sizes[0] / N_DIM;
    const int n_edges = in_sizes[2];
    const int nb = (n_nodes + NPB - 1) / NPB;        // 1563 fine buckets
    const int ncoarse = (n_nodes + 1023) / 1024;     // 98 coarse buckets

    // workspace layout
    unsigned* Y   = (unsigned*)d_ws;                  // n_nodes*16 uints (6.4 MB)
    int* cursorC0 = (int*)(Y + (size_t)n_nodes * 16); // NC_MAX
    int* tmp      = cursorC0 + NC_MAX;                // ncoarse * CAPC (7.2 MB)

    const int nblk_g = (n_nodes + GROWS - 1) / GROWS; // 196
    const int nblk_c = (n_edges + CEPB - 1) / CEPB;   // 391

    // zero coarse cursors (512 B)
    hipMemsetAsync(cursorC0, 0, (size_t)NC_MAX * sizeof(int), stream);

    k_fused<<<nblk_g + nblk_c, FT, 0, stream>>>(X, W, Y, src, dst, cursorC0, tmp,
                                                n_nodes, n_edges, ncoarse, nblk_g);
    k_agg<<<nb, 256, 0, stream>>>((const uint4*)Y, cursorC0, tmp, out, n_nodes);
}

// Round 3
// 123.151 us; speedup vs baseline: 1.1939x; 1.0960x over previous
//
#include <hip/hip_runtime.h>

#define N_DIM 32
#define NPB 64               // fine bucket: nodes per bucket
#define NB_FINE_MAX 2048     // max fine buckets
#define CAPFINE 1280         // pairs slots per fine bucket (mean 1024, +8 sigma)
#define CEPB 4096            // edges per partition block
#define FT 512               // fused kernel threads
#define GROWS 512            // gemm rows per block (FT threads, 1 row/thread)

__device__ __forceinline__ unsigned f2bf_rne(float f) {
    unsigned u = __float_as_uint(f);
    return (u + 0x7FFFu + ((u >> 16) & 1u)) >> 16;
}
__device__ __forceinline__ float bf2f(unsigned h) {
    return __uint_as_float(h << 16);
}

// ---- Fused pass: blocks [0,nblk_g) = GEMM (Y=X@W -> bf16 rows);
// ----             blocks [nblk_g,..) = DIRECT fine partition (1563 bins). ----
__global__ __launch_bounds__(FT) void k_fused(const float* __restrict__ X,
                                              const float* __restrict__ W,
                                              unsigned* __restrict__ Y,
                                              const int* __restrict__ src,
                                              const int* __restrict__ dst,
                                              int* __restrict__ cursorF0,
                                              int* __restrict__ pairs,
                                              int n_nodes, int n_edges,
                                              int nb_fine, int nblk_g) {
    __shared__ float Wlds[N_DIM * N_DIM];
    __shared__ int h[NB_FINE_MAX];
    __shared__ int gb[NB_FINE_MAX];
    const int t = threadIdx.x;

    if (blockIdx.x < nblk_g) {
        // ---------------- GEMM half ----------------
        for (int i = t; i < N_DIM * N_DIM; i += FT) Wlds[i] = W[i];
        __syncthreads();
        const int r = blockIdx.x * GROWS + t;
        if (r >= n_nodes) return;

        float x[N_DIM];
        const float4* xr = (const float4*)(X + (size_t)r * N_DIM);
#pragma unroll
        for (int i = 0; i < N_DIM / 4; ++i) {
            float4 v = xr[i];
            x[4 * i + 0] = v.x; x[4 * i + 1] = v.y;
            x[4 * i + 2] = v.z; x[4 * i + 3] = v.w;
        }
        float acc[N_DIM];
#pragma unroll
        for (int c = 0; c < N_DIM; ++c) acc[c] = 0.0f;
#pragma unroll
        for (int k = 0; k < N_DIM; ++k) {
            const float xk = x[k];
#pragma unroll
            for (int c = 0; c < N_DIM; ++c)
                acc[c] = fmaf(xk, Wlds[k * N_DIM + c], acc[c]);
        }
        unsigned yp[16];
#pragma unroll
        for (int q = 0; q < 16; ++q)
            yp[q] = f2bf_rne(acc[2 * q]) | (f2bf_rne(acc[2 * q + 1]) << 16);
        uint4* yr = (uint4*)(Y + (size_t)r * 16);
#pragma unroll
        for (int i = 0; i < 4; ++i)
            yr[i] = make_uint4(yp[4 * i], yp[4 * i + 1],
                               yp[4 * i + 2], yp[4 * i + 3]);
    } else {
        // ---------------- direct fine-partition half ----------------
        for (int i = t; i < nb_fine; i += FT) h[i] = 0;
        __syncthreads();
        const int start = (blockIdx.x - nblk_g) * CEPB;

        // pack: src (17b) | local-node-in-fine-bucket (6b) << 17; bin = dst>>6
        int vw[CEPB / FT], cw[CEPB / FT], rw[CEPB / FT];
#pragma unroll
        for (int k = 0; k < CEPB / FT; ++k) {
            int e = start + t + k * FT;
            if (e < n_edges) {
                int d = dst[e];
                int c = d >> 6;
                cw[k] = c;
                vw[k] = src[e] | ((d & 63) << 17);
                rw[k] = atomicAdd(&h[c], 1);
            } else {
                cw[k] = -1;
            }
        }
        __syncthreads();
        for (int i = t; i < nb_fine; i += FT) {
            int c = h[i];
            gb[i] = c ? atomicAdd(&cursorF0[i], c) : 0;
        }
        __syncthreads();
#pragma unroll
        for (int k = 0; k < CEPB / FT; ++k)
            if (cw[k] >= 0) {
                int idx = gb[cw[k]] + rw[k];
                if (idx < CAPFINE)
                    pairs[(size_t)cw[k] * CAPFINE + idx] = vw[k];
            }
    }
}

// ---- Aggregate: single-pass per-fine-bucket counting-sort + reg accumulate ----
__device__ __forceinline__ void addv(float* acc, uint4 v) {
    acc[0] += bf2f(v.x & 0xFFFFu); acc[1] += bf2f(v.x >> 16);
    acc[2] += bf2f(v.y & 0xFFFFu); acc[3] += bf2f(v.y >> 16);
    acc[4] += bf2f(v.z & 0xFFFFu); acc[5] += bf2f(v.z >> 16);
    acc[6] += bf2f(v.w & 0xFFFFu); acc[7] += bf2f(v.w >> 16);
}

__global__ __launch_bounds__(256) void k_agg(const uint4* __restrict__ Y4,
                                             const int* __restrict__ cursorF0,
                                             const int* __restrict__ pairs,
                                             float* __restrict__ out,
                                             int n_nodes) {
    __shared__ int sbin[CAPFINE];
    __shared__ int cnt[NPB];
    __shared__ int cst[NPB];
    __shared__ int excl[NPB];

    const int t = threadIdx.x;
    const int b = blockIdx.x;
    const int len = min(cursorF0[b], CAPFINE);
    const size_t segbase = (size_t)b * CAPFINE;
    const int g = t >> 2;          // local node 0..63
    const int l = t & 3;           // quarter-row (16 B)

    if (t < NPB) cnt[t] = 0;
    __syncthreads();

    int pv[CAPFINE / 256], rv[CAPFINE / 256];
#pragma unroll
    for (int k = 0; k < CAPFINE / 256; ++k) {
        int i = t + k * 256;
        if (i < len) {
            int p = pairs[segbase + i];
            pv[k] = p;
            rv[k] = atomicAdd(&cnt[p >> 17], 1);
        } else {
            pv[k] = -1;
        }
    }
    __syncthreads();
    // inclusive scan of 64 counts in wave 0
    if (t < 64) {
        int c0 = cnt[t];
        int c = c0;
#pragma unroll
        for (int off = 1; off < 64; off <<= 1) {
            int u = __shfl_up(c, off, 64);
            if (t >= off) c += u;
        }
        cst[t] = c;
        excl[t] = c - c0;
    }
    __syncthreads();
#pragma unroll
    for (int k = 0; k < CAPFINE / 256; ++k) {
        if (pv[k] >= 0) {
            int p = pv[k];
            sbin[excl[p >> 17] + rv[k]] = p & 0x1FFFF;
        }
    }
    __syncthreads();

    float acc[8];
#pragma unroll
    for (int i = 0; i < 8; ++i) acc[i] = 0.0f;

    // each group consumes its node's segment; 4 gathers in flight
    const int s1 = cst[g];
    const int s0 = s1 - cnt[g];
    for (int e = s0; e < s1; e += 4) {
        const int m = s1 - e;
        int i0 = sbin[e];
        int i1 = sbin[e + ((m > 1) ? 1 : 0)];
        int i2 = sbin[e + ((m > 2) ? 2 : 0)];
        int i3 = sbin[e + ((m > 3) ? 3 : 0)];
        uint4 v0 = Y4[(size_t)i0 * 4 + l];
        uint4 v1 = Y4[(size_t)i1 * 4 + l];
        uint4 v2 = Y4[(size_t)i2 * 4 + l];
        uint4 v3 = Y4[(size_t)i3 * 4 + l];
        addv(acc, v0);
        if (m > 1) addv(acc, v1);
        if (m > 2) addv(acc, v2);
        if (m > 3) addv(acc, v3);
    }

    const int node = b * NPB + g;
    if (node < n_nodes) {
        ((float4*)out)[(size_t)node * 8 + 2 * l] =
            make_float4(acc[0], acc[1], acc[2], acc[3]);
        ((float4*)out)[(size_t)node * 8 + 2 * l + 1] =
            make_float4(acc[4], acc[5], acc[6], acc[7]);
    }
}

extern "C" void kernel_launch(void* const* d_in, const int* in_sizes, int n_in,
                              void* d_out, int out_size, void* d_ws, size_t ws_size,
                              hipStream_t stream) {
    const float* X   = (const float*)d_in[0];
    const float* W   = (const float*)d_in[1];
    const int*   src = (const int*)d_in[2];
    const int*   dst = (const int*)d_in[3];
    float* out = (float*)d_out;

    const int n_nodes = in_sizes[0] / N_DIM;
    const int n_edges = in_sizes[2];
    const int nb = (n_nodes + NPB - 1) / NPB;        // 1563 fine buckets

    // workspace layout
    unsigned* Y   = (unsigned*)d_ws;                  // n_nodes*16 uints (6.4 MB)
    int* cursorF0 = (int*)(Y + (size_t)n_nodes * 16); // NB_FINE_MAX
    int* pairs    = cursorF0 + NB_FINE_MAX;           // nb * CAPFINE (8.0 MB)

    const int nblk_g = (n_nodes + GROWS - 1) / GROWS; // 196
    const int nblk_c = (n_edges + CEPB - 1) / CEPB;   // 391

    // zero fine cursors (6.3 KB)
    hipMemsetAsync(cursorF0, 0, (size_t)NB_FINE_MAX * sizeof(int), stream);

    k_fused<<<nblk_g + nblk_c, FT, 0, stream>>>(X, W, Y, src, dst, cursorF0, pairs,
                                                n_nodes, n_edges, nb, nblk_g);
    k_agg<<<nb, 256, 0, stream>>>((const uint4*)Y, cursorF0, pairs, out, n_nodes);
}